// Round 3
// baseline (69.934 us; speedup 1.0000x reference)
//
#include <hip/hip_runtime.h>

// 5-wire circuit, 100000 single-qubit rotations, batch 64. All gates are
// 1-qubit -> per-wire ordered SU(2) products == unit quaternion products.
// Single fused kernel: 128 blocks compute ordered chunk partials; the last
// block (atomic ticket) reduces the 128 partials and writes all 320 outputs.

#define N_WIRES 5
#define BATCH 64
#define NBLK 128
#define NTHR 256
#define LANES (NBLK * NTHR)
#define CHUNK 4                  // LANES*CHUNK = 131072 >= 100000
#define QTUP (N_WIRES * 4)       // 5 quaternions = 20 floats
#define NWAVE (NTHR / 64)

// r = b (x) a   (b = later gates, multiplies on the LEFT)
__device__ __forceinline__ void qmul(float* r, const float* b, const float* a) {
    r[0] = b[0]*a[0] - b[1]*a[1] - b[2]*a[2] - b[3]*a[3];
    r[1] = b[0]*a[1] + b[1]*a[0] + b[2]*a[3] - b[3]*a[2];
    r[2] = b[0]*a[2] - b[1]*a[3] + b[2]*a[0] + b[3]*a[1];
    r[3] = b[0]*a[3] + b[1]*a[2] - b[2]*a[1] + b[3]*a[0];
}

// Order-preserving adjacent-pair scan across one wave; lane 0 exact product
// of the wave's 64 chunks (later chunks multiplied on the left).
__device__ __forceinline__ void wave_reduce6(float* t) {
    for (int st = 1; st < 64; st <<= 1) {
        float o[QTUP];
        #pragma unroll
        for (int i = 0; i < QTUP; ++i) o[i] = __shfl_down(t[i], st, 64);
        #pragma unroll
        for (int w = 0; w < N_WIRES; ++w) {
            float r[4];
            qmul(r, &o[4*w], &t[4*w]);
            t[4*w+0] = r[0]; t[4*w+1] = r[1]; t[4*w+2] = r[2]; t[4*w+3] = r[3];
        }
    }
}

__global__ __launch_bounds__(NTHR)
void circuit_fused(const float* __restrict__ x,
                   const float* __restrict__ angles,
                   const int*   __restrict__ wires,
                   const int*   __restrict__ types,
                   int n_ops,
                   float* __restrict__ ws,     // NBLK*QTUP partials
                   int*   __restrict__ ticket, // pre-zeroed 4 bytes
                   float* __restrict__ out)
{
    const int tid  = threadIdx.x;
    const int lane = blockIdx.x * NTHR + tid;

    // 5 per-wire quaternion accumulators, init identity (1,0,0,0)
    float acc[N_WIRES][4];
    #pragma unroll
    for (int w = 0; w < N_WIRES; ++w) {
        acc[w][0] = 1.f; acc[w][1] = 0.f; acc[w][2] = 0.f; acc[w][3] = 0.f;
    }

    const int g0 = lane * CHUNK;
    if (g0 < n_ops) {
        float ang[CHUNK]; int wv[CHUNK], tv[CHUNK];
        float sv[CHUNK], cv[CHUNK];
        if (g0 + CHUNK <= n_ops) {
            const float4 a4 = *reinterpret_cast<const float4*>(angles + g0);
            const int4   w4 = *reinterpret_cast<const int4*>(wires + g0);
            const int4   t4 = *reinterpret_cast<const int4*>(types + g0);
            ang[0]=a4.x; ang[1]=a4.y; ang[2]=a4.z; ang[3]=a4.w;
            wv[0]=w4.x;  wv[1]=w4.y;  wv[2]=w4.z;  wv[3]=w4.w;
            tv[0]=t4.x;  tv[1]=t4.y;  tv[2]=t4.z;  tv[3]=t4.w;
            #pragma unroll
            for (int j = 0; j < CHUNK; ++j) __sincosf(0.5f*ang[j], &sv[j], &cv[j]);
        } else {
            #pragma unroll
            for (int j = 0; j < CHUNK; ++j) {
                const int g = g0 + j;
                const bool v = (g < n_ops);
                ang[j] = v ? angles[g] : 0.f;
                wv[j]  = v ? wires[g]  : 0;
                tv[j]  = v ? types[g]  : 0;
                __sincosf(0.5f*ang[j], &sv[j], &cv[j]);
                if (!v) { sv[j] = 0.f; cv[j] = 1.f; }   // identity gate
            }
        }
        #pragma unroll
        for (int j = 0; j < CHUNK; ++j) {
            const int w = wv[j], t = tv[j];
            const float s = sv[j], c = cv[j];
            // branchless gather acc[w] -> q
            float qw = acc[0][0], qx = acc[0][1], qy = acc[0][2], qz = acc[0][3];
            #pragma unroll
            for (int k = 1; k < N_WIRES; ++k) {
                const bool m = (w == k);
                qw = m ? acc[k][0] : qw;  qx = m ? acc[k][1] : qx;
                qy = m ? acc[k][2] : qy;  qz = m ? acc[k][3] : qz;
            }
            // p = e_t (x) q (signed permutation), q' = c*q + s*p
            const float pw = (t == 0) ? -qx : (t == 1) ? -qy : -qz;
            const float px = (t == 0) ?  qw : (t == 1) ?  qz : -qy;
            const float py = (t == 0) ? -qz : (t == 1) ?  qw :  qx;
            const float pz = (t == 0) ?  qy : (t == 1) ? -qx :  qw;
            const float nw = c*qw + s*pw;
            const float nx = c*qx + s*px;
            const float ny = c*qy + s*py;
            const float nz = c*qz + s*pz;
            #pragma unroll
            for (int k = 0; k < N_WIRES; ++k) {
                const bool m = (w == k);
                acc[k][0] = m ? nw : acc[k][0];  acc[k][1] = m ? nx : acc[k][1];
                acc[k][2] = m ? ny : acc[k][2];  acc[k][3] = m ? nz : acc[k][3];
            }
        }
    }

    // intra-wave ordered reduction
    float t[QTUP];
    #pragma unroll
    for (int i = 0; i < QTUP; ++i) t[i] = acc[i >> 2][i & 3];
    wave_reduce6(t);

    // cross-wave combine (in order), thread 0 writes block partial
    __shared__ float lds[NWAVE][QTUP];
    __shared__ int   is_last;
    const int wave = tid >> 6;
    if ((tid & 63) == 0) {
        #pragma unroll
        for (int i = 0; i < QTUP; ++i) lds[wave][i] = t[i];
    }
    __syncthreads();
    if (tid == 0) {
        float r[QTUP];
        #pragma unroll
        for (int i = 0; i < QTUP; ++i) r[i] = lds[0][i];
        #pragma unroll
        for (int v = 1; v < NWAVE; ++v) {
            #pragma unroll
            for (int w = 0; w < N_WIRES; ++w) {
                float z[4];
                qmul(z, &lds[v][4*w], &r[4*w]);
                r[4*w+0]=z[0]; r[4*w+1]=z[1]; r[4*w+2]=z[2]; r[4*w+3]=z[3];
            }
        }
        #pragma unroll
        for (int i = 0; i < QTUP; ++i) ws[blockIdx.x * QTUP + i] = r[i];
        __threadfence();                        // release partial to device scope
        const int tk = atomicAdd(ticket, 1);    // device-scope
        is_last = (tk == NBLK - 1);
    }
    __syncthreads();
    if (!is_last) return;

    // ---- last-arriving block finalizes ----
    __threadfence();                            // acquire: invalidate stale cache
    __shared__ float U[QTUP];
    float p[QTUP];
    if (tid < NBLK) {                           // 2 full waves, 128 partials
        #pragma unroll
        for (int i = 0; i < QTUP; ++i) p[i] = ws[tid * QTUP + i];
        wave_reduce6(p);
        if ((tid & 63) == 0) {
            #pragma unroll
            for (int i = 0; i < QTUP; ++i) lds[tid >> 6][i] = p[i];
        }
    }
    __syncthreads();
    if (tid == 0) {
        #pragma unroll
        for (int w = 0; w < N_WIRES; ++w) {
            float z[4];
            qmul(z, &lds[1][4*w], &lds[0][4*w]);   // later half on the left
            U[4*w+0]=z[0]; U[4*w+1]=z[1]; U[4*w+2]=z[2]; U[4*w+3]=z[3];
        }
    }
    __syncthreads();

    // out[b,k] = 2*Im(conj(v0) v1), v = U_k * [cos(x/2), -i sin(x/2)]^T
    // U from quaternion (w,x,y,z): U00=(w,-z) U01=(-y,-x) U10=(y,-x) U11=(w,z)
    for (int o = tid; o < BATCH * N_WIRES; o += NTHR) {
        const int k = o % N_WIRES;
        const float xv = x[o];
        float sx, cx;
        __sincosf(0.5f * xv, &sx, &cx);
        const float* q = &U[4*k];
        const float v0r =  cx*q[0] - sx*q[1];
        const float v0i = -cx*q[3] + sx*q[2];
        const float v1r =  cx*q[2] + sx*q[3];
        const float v1i = -cx*q[1] - sx*q[0];
        out[o] = 2.f * (v0r * v1i - v0i * v1r);
    }
}

extern "C" void kernel_launch(void* const* d_in, const int* in_sizes, int n_in,
                              void* d_out, int out_size, void* d_ws, size_t ws_size,
                              hipStream_t stream) {
    const float* x      = (const float*)d_in[0];
    const float* angles = (const float*)d_in[1];
    const int*   wires  = (const int*)d_in[2];
    const int*   types  = (const int*)d_in[3];
    float* out = (float*)d_out;
    float* ws  = (float*)d_ws;                       // NBLK*QTUP floats
    int* ticket = (int*)((char*)d_ws + NBLK * QTUP * sizeof(float));

    const int n_ops = in_sizes[1];

    hipMemsetAsync(ticket, 0, sizeof(int), stream);  // graph-capturable memset node
    circuit_fused<<<NBLK, NTHR, 0, stream>>>(x, angles, wires, types, n_ops,
                                             ws, ticket, out);
}

// Round 4
// 66.551 us; speedup vs baseline: 1.0508x; 1.0508x over previous
//
#include <hip/hip_runtime.h>

// 5-wire circuit, 100000 single-qubit rotations, batch 64. All gates are
// 1-qubit -> the circuit factorizes per wire into ordered SU(2) products,
// i.e. unit-quaternion products (gate update = signed permutation + 4 FMA).
// Two-kernel structure (measured faster than ticket-fused single kernel):
//   A: 128 blocks x 256 lanes, CHUNK=4 gates/lane, vectorized loads,
//      wave shuffle-scan + tiny LDS combine -> 128 block partials in ws.
//   B: one block reduces 128 partials (ordered) and writes all 320 outputs.

#define N_WIRES 5
#define BATCH 64
#define NBLK 128
#define NTHR 256
#define LANES (NBLK * NTHR)
#define CHUNK 4                  // LANES*CHUNK = 131072 >= 100000
#define QTUP (N_WIRES * 4)       // 5 quaternions = 20 floats
#define NWAVE (NTHR / 64)

// r = b (x) a   (b = later gates, multiplies on the LEFT)
__device__ __forceinline__ void qmul(float* r, const float* b, const float* a) {
    r[0] = b[0]*a[0] - b[1]*a[1] - b[2]*a[2] - b[3]*a[3];
    r[1] = b[0]*a[1] + b[1]*a[0] + b[2]*a[3] - b[3]*a[2];
    r[2] = b[0]*a[2] - b[1]*a[3] + b[2]*a[0] + b[3]*a[1];
    r[3] = b[0]*a[3] + b[1]*a[2] - b[2]*a[1] + b[3]*a[0];
}

// Order-preserving adjacent-pair scan across one wave; lane 0 ends with the
// exact ordered product of the wave's 64 chunks (later chunks on the left).
__device__ __forceinline__ void wave_reduce6(float* t) {
    for (int st = 1; st < 64; st <<= 1) {
        float o[QTUP];
        #pragma unroll
        for (int i = 0; i < QTUP; ++i) o[i] = __shfl_down(t[i], st, 64);
        #pragma unroll
        for (int w = 0; w < N_WIRES; ++w) {
            float r[4];
            qmul(r, &o[4*w], &t[4*w]);
            t[4*w+0] = r[0]; t[4*w+1] = r[1]; t[4*w+2] = r[2]; t[4*w+3] = r[3];
        }
    }
}

__global__ __launch_bounds__(NTHR)
void gate_partials(const float* __restrict__ angles,
                   const int*   __restrict__ wires,
                   const int*   __restrict__ types,
                   int n_ops,
                   float* __restrict__ ws)
{
    const int tid  = threadIdx.x;
    const int lane = blockIdx.x * NTHR + tid;

    // 5 per-wire quaternion accumulators, init identity (1,0,0,0)
    float acc[N_WIRES][4];
    #pragma unroll
    for (int w = 0; w < N_WIRES; ++w) {
        acc[w][0] = 1.f; acc[w][1] = 0.f; acc[w][2] = 0.f; acc[w][3] = 0.f;
    }

    const int g0 = lane * CHUNK;
    if (g0 < n_ops) {
        float ang[CHUNK]; int wv[CHUNK], tv[CHUNK];
        float sv[CHUNK], cv[CHUNK];
        if (g0 + CHUNK <= n_ops) {
            const float4 a4 = *reinterpret_cast<const float4*>(angles + g0);
            const int4   w4 = *reinterpret_cast<const int4*>(wires + g0);
            const int4   t4 = *reinterpret_cast<const int4*>(types + g0);
            ang[0]=a4.x; ang[1]=a4.y; ang[2]=a4.z; ang[3]=a4.w;
            wv[0]=w4.x;  wv[1]=w4.y;  wv[2]=w4.z;  wv[3]=w4.w;
            tv[0]=t4.x;  tv[1]=t4.y;  tv[2]=t4.z;  tv[3]=t4.w;
            #pragma unroll
            for (int j = 0; j < CHUNK; ++j) __sincosf(0.5f*ang[j], &sv[j], &cv[j]);
        } else {
            #pragma unroll
            for (int j = 0; j < CHUNK; ++j) {
                const int g = g0 + j;
                const bool v = (g < n_ops);
                ang[j] = v ? angles[g] : 0.f;
                wv[j]  = v ? wires[g]  : 0;
                tv[j]  = v ? types[g]  : 0;
                __sincosf(0.5f*ang[j], &sv[j], &cv[j]);
                if (!v) { sv[j] = 0.f; cv[j] = 1.f; }   // identity gate
            }
        }
        #pragma unroll
        for (int j = 0; j < CHUNK; ++j) {
            const int w = wv[j], t = tv[j];
            const float s = sv[j], c = cv[j];
            // branchless gather acc[w] -> q
            float qw = acc[0][0], qx = acc[0][1], qy = acc[0][2], qz = acc[0][3];
            #pragma unroll
            for (int k = 1; k < N_WIRES; ++k) {
                const bool m = (w == k);
                qw = m ? acc[k][0] : qw;  qx = m ? acc[k][1] : qx;
                qy = m ? acc[k][2] : qy;  qz = m ? acc[k][3] : qz;
            }
            // p = e_t (x) q (signed permutation), q' = c*q + s*p
            const float pw = (t == 0) ? -qx : (t == 1) ? -qy : -qz;
            const float px = (t == 0) ?  qw : (t == 1) ?  qz : -qy;
            const float py = (t == 0) ? -qz : (t == 1) ?  qw :  qx;
            const float pz = (t == 0) ?  qy : (t == 1) ? -qx :  qw;
            const float nw = c*qw + s*pw;
            const float nx = c*qx + s*px;
            const float ny = c*qy + s*py;
            const float nz = c*qz + s*pz;
            #pragma unroll
            for (int k = 0; k < N_WIRES; ++k) {
                const bool m = (w == k);
                acc[k][0] = m ? nw : acc[k][0];  acc[k][1] = m ? nx : acc[k][1];
                acc[k][2] = m ? ny : acc[k][2];  acc[k][3] = m ? nz : acc[k][3];
            }
        }
    }

    // intra-wave ordered reduction
    float t[QTUP];
    #pragma unroll
    for (int i = 0; i < QTUP; ++i) t[i] = acc[i >> 2][i & 3];
    wave_reduce6(t);

    // cross-wave combine (in order), thread 0 writes the block partial
    __shared__ float lds[NWAVE][QTUP];
    const int wave = tid >> 6;
    if ((tid & 63) == 0) {
        #pragma unroll
        for (int i = 0; i < QTUP; ++i) lds[wave][i] = t[i];
    }
    __syncthreads();
    if (tid == 0) {
        float r[QTUP];
        #pragma unroll
        for (int i = 0; i < QTUP; ++i) r[i] = lds[0][i];
        #pragma unroll
        for (int v = 1; v < NWAVE; ++v) {
            #pragma unroll
            for (int w = 0; w < N_WIRES; ++w) {
                float z[4];
                qmul(z, &lds[v][4*w], &r[4*w]);
                r[4*w+0]=z[0]; r[4*w+1]=z[1]; r[4*w+2]=z[2]; r[4*w+3]=z[3];
            }
        }
        #pragma unroll
        for (int i = 0; i < QTUP; ++i) ws[blockIdx.x * QTUP + i] = r[i];
    }
}

// Reduce 128 block partials (ordered: 2 wave-scans + 1 combine), then all
// 320 outputs. U from quaternion (w,x,y,z):
//   U00=(w,-z) U01=(-y,-x) U10=(y,-x) U11=(w,z)
// v = U * [cos(x/2), -i sin(x/2)]^T ; out = 2*Im(conj(v0) v1)
__global__ __launch_bounds__(320)
void finalize(const float* __restrict__ x,
              const float* __restrict__ ws,
              float* __restrict__ out)
{
    __shared__ float lds[2][QTUP];
    __shared__ float U[QTUP];
    const int tid = threadIdx.x;
    if (tid < NBLK) {                  // 2 full waves, 128 partials
        float p[QTUP];
        #pragma unroll
        for (int i = 0; i < QTUP; ++i) p[i] = ws[tid * QTUP + i];
        wave_reduce6(p);
        if ((tid & 63) == 0) {
            #pragma unroll
            for (int i = 0; i < QTUP; ++i) lds[tid >> 6][i] = p[i];
        }
    }
    __syncthreads();
    if (tid == 0) {
        #pragma unroll
        for (int w = 0; w < N_WIRES; ++w) {
            float z[4];
            qmul(z, &lds[1][4*w], &lds[0][4*w]);   // later half on the left
            U[4*w+0]=z[0]; U[4*w+1]=z[1]; U[4*w+2]=z[2]; U[4*w+3]=z[3];
        }
    }
    __syncthreads();

    if (tid < BATCH * N_WIRES) {
        const int k = tid % N_WIRES;
        const float xv = x[tid];
        float sx, cx;
        __sincosf(0.5f * xv, &sx, &cx);
        const float* q = &U[4*k];
        const float v0r =  cx*q[0] - sx*q[1];
        const float v0i = -cx*q[3] + sx*q[2];
        const float v1r =  cx*q[2] + sx*q[3];
        const float v1i = -cx*q[1] - sx*q[0];
        out[tid] = 2.f * (v0r * v1i - v0i * v1r);
    }
}

extern "C" void kernel_launch(void* const* d_in, const int* in_sizes, int n_in,
                              void* d_out, int out_size, void* d_ws, size_t ws_size,
                              hipStream_t stream) {
    const float* x      = (const float*)d_in[0];
    const float* angles = (const float*)d_in[1];
    const int*   wires  = (const int*)d_in[2];
    const int*   types  = (const int*)d_in[3];
    float* out = (float*)d_out;
    float* ws  = (float*)d_ws;   // uses NBLK*QTUP*4 = 10240 bytes

    const int n_ops = in_sizes[1];

    gate_partials<<<NBLK, NTHR, 0, stream>>>(angles, wires, types, n_ops, ws);
    finalize<<<1, 320, 0, stream>>>(x, ws, out);
}